// Round 1
// 59.461 us; speedup vs baseline: 1.0667x; 1.0667x over previous
//
#include <hip/hip_runtime.h>
#include <math.h>

// Problem constants (from reference): N=4, E=64, L=512, D=256
#define PN 4
#define PE 64
#define PL 512
#define PD 256
#define NW 16                    // 16 waves = 1024 threads (4 per SIMD)
#define NTHREADS (64 * NW)

// One block per (n,e). Sparse gather version: mask density ~10%, so instead of
// dense-streaming the full 512 KB doc slice per block (L2-port bound, ~3.5 us),
// compact the ~51 selected token indices (wave ballot + prefix, deterministic)
// and gather only those 1 KB rows (~53 KB per block, 10x less L2 traffic).
// Zeros from unselected tokens participate in the max analytically:
//   max_all = max(max_selected, 0) iff count < L;  count==0 -> max=0, mean=0.
__global__ __launch_bounds__(NTHREADS) void MeanMaxPooling_84473416778475_kernel(
    const float* __restrict__ doc_state,      // N x L x D
    const float* __restrict__ nodes_mapping,  // N x E x L
    const float* __restrict__ nodes_len,      // N x E
    float* __restrict__ out)                  // N x E x 2D
{
    const int ne   = blockIdx.x;     // 0..N*E-1
    const int n    = ne >> 6;        // / 64
    const int e    = ne & 63;        // % 64
    const int tid  = threadIdx.x;    // 0..1023
    const int w    = tid >> 6;       // wave 0..15
    const int lane = tid & 63;       // float4 index along D (64 * 4 = 256)

    __shared__ int    sidx[PL];          // compacted selected-token indices (2 KB)
    __shared__ int    wcnt[NW];
    __shared__ int    woff[NW];
    __shared__ int    stotal;
    __shared__ float4 s_sum[NW][64];     // 16 KB
    __shared__ float4 s_max[NW][64];     // 16 KB

    // --- Compaction: waves 0..7 cover the 512 tokens; waves 8..15 ballot 0. ---
    bool sel = false;
    if (tid < PL) {
        const float m = nodes_mapping[(size_t)(n * PE + e) * PL + tid];
        sel = (m > 0.5f);                // mask is exactly 0.0 or 1.0
    }
    const unsigned long long b = __ballot(sel);   // 64-bit wave ballot
    if (lane == 0) wcnt[w] = (int)__popcll(b);
    __syncthreads();
    if (tid == 0) {
        int acc = 0;
        #pragma unroll
        for (int j = 0; j < NW; ++j) { woff[j] = acc; acc += wcnt[j]; }
        stotal = acc;
    }
    __syncthreads();
    if (sel) {
        const int pos = woff[w] + (int)__popcll(b & ((1ull << lane) - 1ull));
        sidx[pos] = tid;                 // token index l == tid (tid < 512 here)
    }
    __syncthreads();

    const int total = stotal;            // == nodes_len (exact small int)

    // doc_state for doc n, viewed as float4 [L][64]
    const float4* __restrict__ ds = (const float4*)(doc_state + (size_t)n * PL * PD);

    float4 sum = make_float4(0.f, 0.f, 0.f, 0.f);
    float4 mx  = make_float4(-INFINITY, -INFINITY, -INFINITY, -INFINITY);

    auto acc1 = [&](const float4 s) {
        sum.x += s.x; sum.y += s.y; sum.z += s.z; sum.w += s.w;
        mx.x = fmaxf(mx.x, s.x);
        mx.y = fmaxf(mx.y, s.y);
        mx.z = fmaxf(mx.z, s.z);
        mx.w = fmaxf(mx.w, s.w);
    };

    // --- Gather only selected rows; rows are 1 KB (64 lanes x float4), coalesced.
    // 4-way unrolled so 4 independent L2 gathers are in flight per wave.
    int i = w;
    for (; i + 3 * NW < total; i += 4 * NW) {
        const int l0 = sidx[i];
        const int l1 = sidx[i + NW];
        const int l2 = sidx[i + 2 * NW];
        const int l3 = sidx[i + 3 * NW];
        const float4 s0 = ds[l0 * 64 + lane];
        const float4 s1 = ds[l1 * 64 + lane];
        const float4 s2 = ds[l2 * 64 + lane];
        const float4 s3 = ds[l3 * 64 + lane];
        acc1(s0); acc1(s1); acc1(s2); acc1(s3);
    }
    for (; i < total; i += NW) {
        const float4 s = ds[sidx[i] * 64 + lane];
        acc1(s);
    }

    s_sum[w][lane] = sum;
    s_max[w][lane] = mx;
    __syncthreads();

    // --- Wave 0 reduces the 16 per-wave partials and writes the output. ---
    if (tid < 64) {
        float4 tsum = s_sum[0][lane];
        float4 tmax = s_max[0][lane];
        #pragma unroll
        for (int j = 1; j < NW; ++j) {
            const float4 s2 = s_sum[j][lane];
            const float4 m2 = s_max[j][lane];
            tsum.x += s2.x; tsum.y += s2.y; tsum.z += s2.z; tsum.w += s2.w;
            tmax.x = fmaxf(tmax.x, m2.x);
            tmax.y = fmaxf(tmax.y, m2.y);
            tmax.z = fmaxf(tmax.z, m2.z);
            tmax.w = fmaxf(tmax.w, m2.w);
        }
        // Unselected tokens contribute exact 0 to the max (mask * state == 0).
        if (total < PL) {
            tmax.x = fmaxf(tmax.x, 0.f);
            tmax.y = fmaxf(tmax.y, 0.f);
            tmax.z = fmaxf(tmax.z, 0.f);
            tmax.w = fmaxf(tmax.w, 0.f);
        }
        const float len  = nodes_len[n * PE + e];
        const float slen = (len > 0.f) ? len : 1.0f;
        float4 mean;
        mean.x = tsum.x / slen;
        mean.y = tsum.y / slen;
        mean.z = tsum.z / slen;
        mean.w = tsum.w / slen;

        float4* o = (float4*)(out + (size_t)(n * PE + e) * 2 * PD);
        o[lane]      = tmax;   // max_pooled -> first D
        o[64 + lane] = mean;   // mean_pooled -> second D
    }
}

extern "C" void kernel_launch(void* const* d_in, const int* in_sizes, int n_in,
                              void* d_out, int out_size, void* d_ws, size_t ws_size,
                              hipStream_t stream) {
    const float* doc_state     = (const float*)d_in[0];  // N*L*D
    const float* nodes_mapping = (const float*)d_in[1];  // N*E*L
    const float* nodes_len     = (const float*)d_in[2];  // N*E
    float* out = (float*)d_out;                          // N*E*2D

    dim3 grid(PN * PE);        // 256 blocks, ~1 per CU
    dim3 block(NTHREADS);      // 1024 threads = 16 waves
    MeanMaxPooling_84473416778475_kernel<<<grid, block, 0, stream>>>(
        doc_state, nodes_mapping, nodes_len, out);
}